// Round 18
// baseline (154.594 us; speedup 1.0000x reference)
//
#include <hip/hip_runtime.h>

#define NB 262144
#define NNODE (NB * 4)
#define EMB_ELEMS ((size_t)NNODE * 64)
#define ADJ_BLOCKS (NNODE / 256)               // 4096

typedef __attribute__((ext_vector_type(8))) _Float16 f16x8;
typedef __attribute__((ext_vector_type(4))) float f32x4;
typedef __attribute__((ext_vector_type(4))) unsigned int u32x4;

// ---- weight-image layout (bytes), strides padded to 16B multiples ----
#define OW1E  0        // [128][40] f16 : W1^T ext (k0..3=W1, k4=b1, pad 0)
#define OW2T  10240    // [64][136] f16 : W2^T, k-cols PERMUTED by pi
#define OW3T  27648    // [64][72]  f16 : W3^T, k-cols PERMUTED by pi
#define OW3GT 36864    // [32][72]  f16 : (W3@Wg1)^T, k-cols PERMUTED by pi
#define OWG2A 41472    // [16][40]  f16 : Wg2^T pi-permuted A-tile (rows 4..15 = 0)
#define OF32  42752    // f32 section
#define IMG_BYTES 43600
// f32 section offsets (floats)
#define FB2   0
#define FB3   64
#define FB3G  128
#define FBG1  160
#define FBG2  192
#define FAHAT 196      // [4][4]

#define NWAVE 4                                 // 256 threads/block (R18)
#define SMEM_BYTES IMG_BYTES                    // 43.6KB -> 3 blocks/CU possible

// pi: k-permutation making MFMA C-frags directly consumable as B-frags
// (validated end-to-end R11-R17).
__device__ __forceinline__ int kperm(int ji) {
    int kt = ji >> 5, r = ji & 31, g = r >> 3, e = r & 7;
    return kt * 32 + ((e >> 2) << 4) + (g << 2) + (e & 3);
}

template <int J>
__device__ __forceinline__ float qb(float v) {      // broadcast quad-lane J (DPP)
    constexpr int ctrl = J | (J << 2) | (J << 4) | (J << 6);
    int r = __builtin_amdgcn_update_dpp(0, __builtin_bit_cast(int, v), ctrl, 0xF, 0xF, true);
    return __builtin_bit_cast(float, r);
}

// ---------------------------------------------------------------------------
// Kernel 1: adjacency union (R15/R17-validated: ballot wave-combine).
// ---------------------------------------------------------------------------
__global__ __launch_bounds__(256) void adj_kernel(const float* __restrict__ x,
                                                  unsigned int* __restrict__ mask_arr) {
    __shared__ unsigned int smask;
    if (threadIdx.x == 0) smask = 0u;
    __syncthreads();

    const int t = blockIdx.x * 256 + threadIdx.x;
    const int c = t & 3;
    f32x4 v = *(const f32x4*)(x + (size_t)t * 4);
    float nn = sqrtf(v.x * v.x + v.y * v.y + v.z * v.z + v.w * v.w);
    float inv = 1.0f / fmaxf(nn, 1e-8f);

    unsigned int m = 0u;
#define DOTJ(J) do {                                                            \
        const float bx = qb<J>(v.x), by = qb<J>(v.y);                           \
        const float bz = qb<J>(v.z), bw = qb<J>(v.w);                           \
        const float bi = qb<J>(inv);                                            \
        const float d = v.x * bx + v.y * by + v.z * bz + v.w * bw;              \
        if ((int)((J) != c) & (int)(d * inv * bi > 0.5f)) {                     \
            const int i_ = c < (J) ? c : (J);                                   \
            const int j_ = c < (J) ? (J) : c;                                   \
            m |= 1u << (2 * i_ + j_ - 1 - (i_ >> 1));                           \
        }                                                                       \
    } while (0)
    DOTJ(0); DOTJ(1); DOTJ(2); DOTJ(3);
#undef DOTJ

    unsigned wm = 0u;
#pragma unroll
    for (int p = 0; p < 6; ++p)
        if (__ballot((m >> p) & 1u)) wm |= (1u << p);
    if ((threadIdx.x & 63) == 0 && wm) atomicOr(&smask, wm);
    __syncthreads();
    if (threadIdx.x == 0) mask_arr[blockIdx.x] = smask;
}

// ---------------------------------------------------------------------------
// Kernel 2: build f16 weight image (k-permuted) + f32 consts. 4 blocks.
// ---------------------------------------------------------------------------
__global__ __launch_bounds__(256) void prep_kernel(
    const float* __restrict__ W1, const float* __restrict__ b1,
    const float* __restrict__ W2, const float* __restrict__ b2,
    const float* __restrict__ W3, const float* __restrict__ b3,
    const float* __restrict__ Wg1, const float* __restrict__ bg1,
    const float* __restrict__ Wg2, const float* __restrict__ bg2,
    const unsigned int* __restrict__ mask_arr, char* __restrict__ img)
{
    const int t = threadIdx.x;
    const int bid = blockIdx.x;
    _Float16* H = (_Float16*)img;
    float* F = (float*)(img + OF32);

    if (bid == 0) {
        __shared__ unsigned red[256];
        unsigned um = 0u;
        for (int i = t; i < ADJ_BLOCKS; i += 256) um |= mask_arr[i];
        red[t] = um;
        __syncthreads();
        for (int s = 128; s > 0; s >>= 1) {
            if (t < s) red[t] |= red[t + s];
            __syncthreads();
        }
        const unsigned m = red[0];

        for (int i = t; i < 64; i += 256) F[FB2 + i] = b2[i];
        for (int i = t; i < 64; i += 256) F[FB3 + i] = b3[i];
        for (int i = t; i < 32; i += 256) {
            float s = 0.f;
            for (int h = 0; h < 64; ++h) s = fmaf(b3[h], Wg1[h * 32 + i], s);
            F[FB3G + i] = s;
        }
        for (int i = t; i < 32; i += 256) F[FBG1 + i] = bg1[i];
        for (int i = t; i < 4; i += 256) F[FBG2 + i] = bg2[i];
        for (int i = t; i < 16 * 40; i += 256) {            // OWG2A: Wg2^T pi-perm
            int o = i / 40, ji = i % 40;
            float v = (o < 4 && ji < 32) ? Wg2[kperm(ji) * 4 + o] : 0.f;
            H[OWG2A / 2 + i] = (_Float16)v;
        }
        if (t == 0) {
            float A[4][4];
            for (int i = 0; i < 4; ++i)
                for (int j = 0; j < 4; ++j) A[i][j] = (i == j) ? 1.f : 0.f;
            int bit = 0;
            for (int i = 0; i < 4; ++i)
                for (int j = i + 1; j < 4; ++j) {
                    if ((m >> bit) & 1u) { A[i][j] = 1.f; A[j][i] = 1.f; }
                    ++bit;
                }
            float dinv[4];
            for (int i = 0; i < 4; ++i)
                dinv[i] = 1.0f / sqrtf(A[i][0] + A[i][1] + A[i][2] + A[i][3]);
            for (int i = 0; i < 4; ++i)
                for (int j = 0; j < 4; ++j) F[FAHAT + i * 4 + j] = dinv[i] * A[i][j] * dinv[j];
        }
    } else if (bid == 1) {
        for (int i = t; i < 128 * 40; i += 256) {           // W1E (k identity)
            int j = i / 40, kk = i % 40;
            float v = (kk < 4) ? W1[kk * 128 + j] : (kk == 4 ? b1[j] : 0.f);
            H[OW1E / 2 + i] = (_Float16)v;
        }
    } else if (bid == 2) {
        for (int i = t; i < 64 * 136; i += 256) {           // W2T, k-cols pi-perm
            int jo = i / 136, ji = i % 136;
            float v = 0.f;
            if (ji < 128) v = W2[kperm(ji) * 64 + jo];
            H[OW2T / 2 + i] = (_Float16)v;
        }
    } else {
        for (int i = t; i < 64 * 72; i += 256) {            // W3T, k-cols pi-perm
            int h = i / 72, j = i % 72;
            float v = 0.f;
            if (j < 64) v = W3[kperm(j) * 64 + h];
            H[OW3T / 2 + i] = (_Float16)v;
        }
        for (int i = t; i < 32 * 72; i += 256) {            // W3GT, k-cols pi-perm
            int e = i / 72, j = i % 72;
            float s = 0.f;
            if (j < 64) {
                const int jj = kperm(j);
                for (int h = 0; h < 64; ++h) s = fmaf(W3[jj * 64 + h], Wg1[h * 32 + e], s);
            }
            H[OW3GT / 2 + i] = (_Float16)s;
        }
    }
}

// ---------------------------------------------------------------------------
// helpers
// ---------------------------------------------------------------------------
__device__ __forceinline__ unsigned pkf16(float a, float b) {
    unsigned short ha = __builtin_bit_cast(unsigned short, (_Float16)a);
    unsigned short hb = __builtin_bit_cast(unsigned short, (_Float16)b);
    return (unsigned)ha | ((unsigned)hb << 16);
}
__device__ __forceinline__ f32x4 MF(f16x8 a, f16x8 b, f32x4 c) {
    return __builtin_amdgcn_mfma_f32_16x16x32_f16(a, b, c, 0, 0, 0);
}
__device__ __forceinline__ f16x8 ldA(const _Float16* p) {
    return *(const f16x8*)p;            // 16B-aligned ds_read_b128
}
__device__ __forceinline__ f16x8 bcat(unsigned X0, unsigned X1,
                                      unsigned Y0, unsigned Y1) {
    u32x4 t; t.x = X0; t.y = X1; t.z = Y0; t.w = Y1;
    return __builtin_bit_cast(f16x8, t);
}

// ---------------------------------------------------------------------------
// Kernel 3: fused MLP+GCN, f16 MFMA. R18: 256 thr = 4 waves/block, LDS =
// image only (43.6KB -> 3 blocks/CU = 12 waves/CU, +50% vs R17's 8).
// emb stored DIRECTLY from C-frags: per (nt,mh), two back-to-back
// global_store_dwordx4 (mt2=0: bytes 0-63, mt2=1: bytes 64-127 of each of
// 16 nodes' 128B lines) — write-combine should merge into full lines
// (R3's RFO had phase-SEPARATED 64B partials; these are ~2 cycles apart).
// No LDS transpose, no tb buffer, shorter per-tile serial chain.
// ---------------------------------------------------------------------------
__global__ __launch_bounds__(256, 2) void mlp_gcn_mfma(
    const float* __restrict__ x, const char* __restrict__ img,
    float* __restrict__ emb_out, float* __restrict__ out_out)
{
    __shared__ u32x4 smem4[(SMEM_BYTES + 15) / 16];
    char* smem = (char*)smem4;
    const int tx = threadIdx.x;
    {   // stage weight image (flat, coalesced)
        const u32x4* src = (const u32x4*)img;
        u32x4* dst = (u32x4*)smem;
        for (int i = tx; i < IMG_BYTES / 16; i += 256) dst[i] = src[i];
    }
    __syncthreads();

    const _Float16* wh = (const _Float16*)smem;
    const float* wf = (const float*)(smem + OF32);

    const int wid = tx >> 6, lane = tx & 63;
    const int g = lane >> 4, c = lane & 15;
    const bool g0 = (g == 0);

    const size_t nbase0 = ((size_t)blockIdx.x * NWAVE + wid) * 128;  // 2 tiles/wave

#pragma unroll 1
    for (int it = 0; it < 2; ++it) {
        const size_t nbase = nbase0 + (size_t)it * 64;

        // ---- xB frags via direct global loads (R13-validated) ----
        f16x8 xB[4];
#pragma unroll
        for (int nt = 0; nt < 4; ++nt) {
            f32x4 xq = *(const f32x4*)(x + (nbase + nt * 16 + c) * 4);
            u32x4 t;
            t.x = g0 ? pkf16(xq.x, xq.y) : 0u;
            t.y = g0 ? pkf16(xq.z, xq.w) : 0u;
            t.z = g0 ? 0x00003C00u : 0u;    // f16 {1.0, 0}
            t.w = 0u;
            xB[nt] = __builtin_bit_cast(f16x8, t);
        }

        // ---- L1+L2 per kt: h1 chunk -> bcat B-frags -> L2 MFMAs ----
        f32x4 acc2[4][4];
#pragma unroll
        for (int mt = 0; mt < 4; ++mt) {
            f32x4 bv = *(const f32x4*)(wf + FB2 + mt * 16 + g * 4);
#pragma unroll
            for (int nt = 0; nt < 4; ++nt) acc2[mt][nt] = bv;
        }
#pragma unroll
        for (int kt = 0; kt < 4; ++kt) {
            f16x8 a0 = ldA(wh + OW1E / 2 + ((2 * kt + 0) * 16 + c) * 40 + g * 8);
            f16x8 a1 = ldA(wh + OW1E / 2 + ((2 * kt + 1) * 16 + c) * 40 + g * 8);
            f16x8 bf[4];
#pragma unroll
            for (int nt = 0; nt < 4; ++nt) {
                f32x4 z = {0.f, 0.f, 0.f, 0.f};
                f32x4 t0 = MF(a0, xB[nt], z);
                f32x4 t1 = MF(a1, xB[nt], z);
                bf[nt] = bcat(pkf16(fmaxf(t0[0], 0.f), fmaxf(t0[1], 0.f)),
                              pkf16(fmaxf(t0[2], 0.f), fmaxf(t0[3], 0.f)),
                              pkf16(fmaxf(t1[0], 0.f), fmaxf(t1[1], 0.f)),
                              pkf16(fmaxf(t1[2], 0.f), fmaxf(t1[3], 0.f)));
            }
#pragma unroll
            for (int mt = 0; mt < 4; ++mt) {
                f16x8 a = ldA(wh + OW2T / 2 + (mt * 16 + c) * 136 + kt * 32 + g * 8);
#pragma unroll
                for (int nt = 0; nt < 4; ++nt) acc2[mt][nt] = MF(a, bf[nt], acc2[mt][nt]);
            }
        }

        // ---- pack h2 (relu); acc2 dies here ----
        unsigned pk2a[4][4][2];
#pragma unroll
        for (int mt = 0; mt < 4; ++mt)
#pragma unroll
            for (int nt = 0; nt < 4; ++nt) {
                pk2a[mt][nt][0] = pkf16(fmaxf(acc2[mt][nt][0], 0.f), fmaxf(acc2[mt][nt][1], 0.f));
                pk2a[mt][nt][1] = pkf16(fmaxf(acc2[mt][nt][2], 0.f), fmaxf(acc2[mt][nt][3], 0.f));
            }

        // ---- tail FIRST: acc4 (tt) + GCN mix + out store ----
        {
            f32x4 acc4[2][4];
#pragma unroll
            for (int mt = 0; mt < 2; ++mt) {
                f32x4 bv = *(const f32x4*)(wf + FB3G + mt * 16 + g * 4);
#pragma unroll
                for (int nt = 0; nt < 4; ++nt) acc4[mt][nt] = bv;
            }
#pragma unroll
            for (int kt = 0; kt < 2; ++kt) {
#pragma unroll
                for (int mt = 0; mt < 2; ++mt) {
                    f16x8 a = ldA(wh + OW3GT / 2 + (mt * 16 + c) * 72 + kt * 32 + g * 8);
#pragma unroll
                    for (int nt = 0; nt < 4; ++nt) {
                        f16x8 bf = bcat(pk2a[2 * kt][nt][0], pk2a[2 * kt][nt][1],
                                        pk2a[2 * kt + 1][nt][0], pk2a[2 * kt + 1][nt][1]);
                        acc4[mt][nt] = MF(a, bf, acc4[mt][nt]);
                    }
                }
            }
            const f32x4 arow = *(const f32x4*)(wf + FAHAT + (c & 3) * 4);
            f32x4 bg1v[2];
            bg1v[0] = *(const f32x4*)(wf + FBG1 + g * 4);
            bg1v[1] = *(const f32x4*)(wf + FBG1 + 16 + g * 4);
            const f32x4 bg2v = *(const f32x4*)(wf + FBG2);
            const f16x8 aWg2 = ldA(wh + OWG2A / 2 + c * 40 + g * 8);
#pragma unroll
            for (int nt = 0; nt < 4; ++nt) {
                float gv[2][4];
#pragma unroll
                for (int m = 0; m < 2; ++m)
#pragma unroll
                    for (int r = 0; r < 4; ++r) {
                        float v = acc4[m][nt][r];
                        float s = bg1v[m][r];
                        s = fmaf(arow.x, qb<0>(v), s);
                        s = fmaf(arow.y, qb<1>(v), s);
                        s = fmaf(arow.z, qb<2>(v), s);
                        s = fmaf(arow.w, qb<3>(v), s);
                        gv[m][r] = fmaxf(s, 0.f);
                    }
                f16x8 bfg = bcat(pkf16(gv[0][0], gv[0][1]), pkf16(gv[0][2], gv[0][3]),
                                 pkf16(gv[1][0], gv[1][1]), pkf16(gv[1][2], gv[1][3]));
                f32x4 z = {0.f, 0.f, 0.f, 0.f};
                f32x4 u4 = MF(aWg2, bfg, z);
                float ov[4];
#pragma unroll
                for (int o = 0; o < 4; ++o) {
                    float s = bg2v[o];
                    s = fmaf(arow.x, qb<0>(u4[o]), s);
                    s = fmaf(arow.y, qb<1>(u4[o]), s);
                    s = fmaf(arow.z, qb<2>(u4[o]), s);
                    s = fmaf(arow.w, qb<3>(u4[o]), s);
                    ov[o] = s;
                }
                if (g0) {
                    f32x4 t; t.x = ov[0]; t.y = ov[1]; t.z = ov[2]; t.w = ov[3];
                    *(f32x4*)(out_out + (nbase + nt * 16 + c) * 4) = t;
                }
            }
        }

        // ---- emb: two mt-halves, DIRECT stores (no LDS transpose) ----
        // lane(g,c) acc3h[mt2][nt][r] = emb[node nt*16+c][mh*32+mt2*16+g*4+r]
        // per (nt,mt2): one dwordx4 covers 64B of 16 nodes' lines; mt2=0/1
        // issued back-to-back complete each 128B line.
#pragma unroll 1
        for (int mh = 0; mh < 2; ++mh) {
            f32x4 acc3h[2][4];
#pragma unroll
            for (int mt2 = 0; mt2 < 2; ++mt2) {
                f32x4 bv = *(const f32x4*)(wf + FB3 + (mh * 2 + mt2) * 16 + g * 4);
#pragma unroll
                for (int nt = 0; nt < 4; ++nt) acc3h[mt2][nt] = bv;
            }
#pragma unroll
            for (int kt = 0; kt < 2; ++kt) {
#pragma unroll
                for (int mt2 = 0; mt2 < 2; ++mt2) {
                    const int mt = mh * 2 + mt2;
                    f16x8 a = ldA(wh + OW3T / 2 + (mt * 16 + c) * 72 + kt * 32 + g * 8);
#pragma unroll
                    for (int nt = 0; nt < 4; ++nt) {
                        f16x8 bf = bcat(pk2a[2 * kt][nt][0], pk2a[2 * kt][nt][1],
                                        pk2a[2 * kt + 1][nt][0], pk2a[2 * kt + 1][nt][1]);
                        acc3h[mt2][nt] = MF(a, bf, acc3h[mt2][nt]);
                    }
                }
            }
#pragma unroll
            for (int nt = 0; nt < 4; ++nt) {
                float* np = emb_out + (nbase + nt * 16 + c) * 64 + mh * 32 + g * 4;
                *(f32x4*)(np) = acc3h[0][nt];          // bytes [0,64) of line
                *(f32x4*)(np + 16) = acc3h[1][nt];     // bytes [64,128) — back-to-back
            }
        }
    }
}

// ---------------------------------------------------------------------------
extern "C" void kernel_launch(void* const* d_in, const int* in_sizes, int n_in,
                              void* d_out, int out_size, void* d_ws, size_t ws_size,
                              hipStream_t stream) {
    const float* x   = (const float*)d_in[0];
    const float* W1  = (const float*)d_in[1];
    const float* b1  = (const float*)d_in[2];
    const float* W2  = (const float*)d_in[3];
    const float* b2  = (const float*)d_in[4];
    const float* W3  = (const float*)d_in[5];
    const float* b3  = (const float*)d_in[6];
    const float* Wg1 = (const float*)d_in[7];
    const float* bg1 = (const float*)d_in[8];
    const float* Wg2 = (const float*)d_in[9];
    const float* bg2 = (const float*)d_in[10];

    unsigned int* mask_arr = (unsigned int*)d_ws;          // 4096 words, all rewritten
    char* img = (char*)d_ws + 16640;                       // past mask array, 256-aligned

    float* emb_out = (float*)d_out;
    float* out_out = emb_out + EMB_ELEMS;

    adj_kernel<<<ADJ_BLOCKS, 256, 0, stream>>>(x, mask_arr);
    prep_kernel<<<4, 256, 0, stream>>>(W1, b1, W2, b2, W3, b3, Wg1, bg1, Wg2, bg2,
                                       mask_arr, img);
    mlp_gcn_mfma<<<NNODE / 512, 256, 0, stream>>>(x, img, emb_out, out_out);
}

// Round 19
// 104.210 us; speedup vs baseline: 1.4835x; 1.4835x over previous
//
#include <hip/hip_runtime.h>

#define NB 262144
#define NNODE (NB * 4)
#define EMB_ELEMS ((size_t)NNODE * 64)
#define ADJ_BLOCKS (NNODE / 256)               // 4096

typedef __attribute__((ext_vector_type(8))) _Float16 f16x8;
typedef __attribute__((ext_vector_type(4))) float f32x4;
typedef __attribute__((ext_vector_type(4))) unsigned int u32x4;

// ---- weight-image layout (bytes), strides padded to 16B multiples ----
#define OW1E  0        // [128][40] f16 : W1^T ext (k0..3=W1, k4=b1, pad 0)
#define OW2T  10240    // [64][136] f16 : W2^T, k-cols PERMUTED by pi
#define OW3T  27648    // [64][72]  f16 : W3^T, k-cols PERMUTED by pi
#define OW3GT 36864    // [32][72]  f16 : (W3@Wg1)^T, k-cols PERMUTED by pi
#define OWG2A 41472    // [16][40]  f16 : Wg2^T pi-permuted A-tile (rows 4..15 = 0)
#define OF32  42752    // f32 section
#define IMG_BYTES 43600
// f32 section offsets (floats)
#define FB2   0
#define FB3   64
#define FB3G  128
#define FBG1  160
#define FBG2  192
#define FAHAT 196      // [4][4]

#define NWAVE 8                                 // 512 threads
#define WBUF_BYTES 4096                         // per-wave transpose buffer
#define SMEM_BYTES (IMG_BYTES + NWAVE * WBUF_BYTES)  // 76368

// pi: k-permutation making MFMA C-frags directly consumable as B-frags
// (validated end-to-end R11-R18).
__device__ __forceinline__ int kperm(int ji) {
    int kt = ji >> 5, r = ji & 31, g = r >> 3, e = r & 7;
    return kt * 32 + ((e >> 2) << 4) + (g << 2) + (e & 3);
}

template <int J>
__device__ __forceinline__ float qb(float v) {      // broadcast quad-lane J (DPP)
    constexpr int ctrl = J | (J << 2) | (J << 4) | (J << 6);
    int r = __builtin_amdgcn_update_dpp(0, __builtin_bit_cast(int, v), ctrl, 0xF, 0xF, true);
    return __builtin_bit_cast(float, r);
}

// ---------------------------------------------------------------------------
// Kernel 1: adjacency union. Ballot wave-combine (R15-validated): 1 LDS
// atomic per wave. DPP broadcasts at FULL exec (R4 lesson).
// ---------------------------------------------------------------------------
__global__ __launch_bounds__(256) void adj_kernel(const float* __restrict__ x,
                                                  unsigned int* __restrict__ mask_arr) {
    __shared__ unsigned int smask;
    if (threadIdx.x == 0) smask = 0u;
    __syncthreads();

    const int t = blockIdx.x * 256 + threadIdx.x;
    const int c = t & 3;
    f32x4 v = *(const f32x4*)(x + (size_t)t * 4);
    float nn = sqrtf(v.x * v.x + v.y * v.y + v.z * v.z + v.w * v.w);
    float inv = 1.0f / fmaxf(nn, 1e-8f);

    unsigned int m = 0u;
#define DOTJ(J) do {                                                            \
        const float bx = qb<J>(v.x), by = qb<J>(v.y);                           \
        const float bz = qb<J>(v.z), bw = qb<J>(v.w);                           \
        const float bi = qb<J>(inv);                                            \
        const float d = v.x * bx + v.y * by + v.z * bz + v.w * bw;              \
        if ((int)((J) != c) & (int)(d * inv * bi > 0.5f)) {                     \
            const int i_ = c < (J) ? c : (J);                                   \
            const int j_ = c < (J) ? (J) : c;                                   \
            m |= 1u << (2 * i_ + j_ - 1 - (i_ >> 1));                           \
        }                                                                       \
    } while (0)
    DOTJ(0); DOTJ(1); DOTJ(2); DOTJ(3);
#undef DOTJ

    unsigned wm = 0u;
#pragma unroll
    for (int p = 0; p < 6; ++p)
        if (__ballot((m >> p) & 1u)) wm |= (1u << p);
    if ((threadIdx.x & 63) == 0 && wm) atomicOr(&smask, wm);
    __syncthreads();
    if (threadIdx.x == 0) mask_arr[blockIdx.x] = smask;
}

// ---------------------------------------------------------------------------
// Kernel 2: build f16 weight image (k-permuted) + f32 consts. 4 blocks.
// ---------------------------------------------------------------------------
__global__ __launch_bounds__(256) void prep_kernel(
    const float* __restrict__ W1, const float* __restrict__ b1,
    const float* __restrict__ W2, const float* __restrict__ b2,
    const float* __restrict__ W3, const float* __restrict__ b3,
    const float* __restrict__ Wg1, const float* __restrict__ bg1,
    const float* __restrict__ Wg2, const float* __restrict__ bg2,
    const unsigned int* __restrict__ mask_arr, char* __restrict__ img)
{
    const int t = threadIdx.x;
    const int bid = blockIdx.x;
    _Float16* H = (_Float16*)img;
    float* F = (float*)(img + OF32);

    if (bid == 0) {
        __shared__ unsigned red[256];
        unsigned um = 0u;
        for (int i = t; i < ADJ_BLOCKS; i += 256) um |= mask_arr[i];
        red[t] = um;
        __syncthreads();
        for (int s = 128; s > 0; s >>= 1) {
            if (t < s) red[t] |= red[t + s];
            __syncthreads();
        }
        const unsigned m = red[0];

        for (int i = t; i < 64; i += 256) F[FB2 + i] = b2[i];
        for (int i = t; i < 64; i += 256) F[FB3 + i] = b3[i];
        for (int i = t; i < 32; i += 256) {
            float s = 0.f;
            for (int h = 0; h < 64; ++h) s = fmaf(b3[h], Wg1[h * 32 + i], s);
            F[FB3G + i] = s;
        }
        for (int i = t; i < 32; i += 256) F[FBG1 + i] = bg1[i];
        for (int i = t; i < 4; i += 256) F[FBG2 + i] = bg2[i];
        for (int i = t; i < 16 * 40; i += 256) {            // OWG2A: Wg2^T pi-perm
            int o = i / 40, ji = i % 40;
            float v = (o < 4 && ji < 32) ? Wg2[kperm(ji) * 4 + o] : 0.f;
            H[OWG2A / 2 + i] = (_Float16)v;
        }
        if (t == 0) {
            float A[4][4];
            for (int i = 0; i < 4; ++i)
                for (int j = 0; j < 4; ++j) A[i][j] = (i == j) ? 1.f : 0.f;
            int bit = 0;
            for (int i = 0; i < 4; ++i)
                for (int j = i + 1; j < 4; ++j) {
                    if ((m >> bit) & 1u) { A[i][j] = 1.f; A[j][i] = 1.f; }
                    ++bit;
                }
            float dinv[4];
            for (int i = 0; i < 4; ++i)
                dinv[i] = 1.0f / sqrtf(A[i][0] + A[i][1] + A[i][2] + A[i][3]);
            for (int i = 0; i < 4; ++i)
                for (int j = 0; j < 4; ++j) F[FAHAT + i * 4 + j] = dinv[i] * A[i][j] * dinv[j];
        }
    } else if (bid == 1) {
        for (int i = t; i < 128 * 40; i += 256) {           // W1E (k identity)
            int j = i / 40, kk = i % 40;
            float v = (kk < 4) ? W1[kk * 128 + j] : (kk == 4 ? b1[j] : 0.f);
            H[OW1E / 2 + i] = (_Float16)v;
        }
    } else if (bid == 2) {
        for (int i = t; i < 64 * 136; i += 256) {           // W2T, k-cols pi-perm
            int jo = i / 136, ji = i % 136;
            float v = 0.f;
            if (ji < 128) v = W2[kperm(ji) * 64 + jo];
            H[OW2T / 2 + i] = (_Float16)v;
        }
    } else {
        for (int i = t; i < 64 * 72; i += 256) {            // W3T, k-cols pi-perm
            int h = i / 72, j = i % 72;
            float v = 0.f;
            if (j < 64) v = W3[kperm(j) * 64 + h];
            H[OW3T / 2 + i] = (_Float16)v;
        }
        for (int i = t; i < 32 * 72; i += 256) {            // W3GT, k-cols pi-perm
            int e = i / 72, j = i % 72;
            float s = 0.f;
            if (j < 64) {
                const int jj = kperm(j);
                for (int h = 0; h < 64; ++h) s = fmaf(W3[jj * 64 + h], Wg1[h * 32 + e], s);
            }
            H[OW3GT / 2 + i] = (_Float16)s;
        }
    }
}

// ---------------------------------------------------------------------------
// helpers
// ---------------------------------------------------------------------------
__device__ __forceinline__ unsigned pkf16(float a, float b) {
    unsigned short ha = __builtin_bit_cast(unsigned short, (_Float16)a);
    unsigned short hb = __builtin_bit_cast(unsigned short, (_Float16)b);
    return (unsigned)ha | ((unsigned)hb << 16);
}
__device__ __forceinline__ f32x4 MF(f16x8 a, f16x8 b, f32x4 c) {
    return __builtin_amdgcn_mfma_f32_16x16x32_f16(a, b, c, 0, 0, 0);
}
__device__ __forceinline__ f16x8 ldA(const _Float16* p) {
    return *(const f16x8*)p;            // 16B-aligned ds_read_b128
}
__device__ __forceinline__ f16x8 bcat(unsigned X0, unsigned X1,
                                      unsigned Y0, unsigned Y1) {
    u32x4 t; t.x = X0; t.y = X1; t.z = Y0; t.w = Y1;
    return __builtin_bit_cast(f16x8, t);
}

// ---------------------------------------------------------------------------
// Kernel 3: fused MLP+GCN, f16 MFMA — R17 config VERBATIM (best measured:
// 105.4us). (512,2) register regime; LDS-transpose emb stores (R18 proved
// direct 64B partial-line stores do NOT write-combine -> RFO penalty).
// ---------------------------------------------------------------------------
__global__ __launch_bounds__(512, 2) void mlp_gcn_mfma(
    const float* __restrict__ x, const char* __restrict__ img,
    float* __restrict__ emb_out, float* __restrict__ out_out)
{
    __shared__ u32x4 smem4[SMEM_BYTES / 16];
    char* smem = (char*)smem4;
    const int tx = threadIdx.x;
    {   // stage weight image (flat, coalesced)
        const u32x4* src = (const u32x4*)img;
        u32x4* dst = (u32x4*)smem;
        for (int i = tx; i < IMG_BYTES / 16; i += 512) dst[i] = src[i];
    }
    __syncthreads();

    const _Float16* wh = (const _Float16*)smem;
    const float* wf = (const float*)(smem + OF32);

    const int wid = tx >> 6, lane = tx & 63;
    const int g = lane >> 4, c = lane & 15;
    const bool g0 = (g == 0);

    float* tb = (float*)(smem + IMG_BYTES) + wid * 1024;   // per-wave buffer

    const size_t nbase0 = ((size_t)blockIdx.x * NWAVE + wid) * 256;  // 4 tiles/wave

#pragma unroll 1
    for (int it = 0; it < 4; ++it) {
        const size_t nbase = nbase0 + (size_t)it * 64;

        // ---- xB frags via direct global loads (R13-validated) ----
        f16x8 xB[4];
#pragma unroll
        for (int nt = 0; nt < 4; ++nt) {
            f32x4 xq = *(const f32x4*)(x + (nbase + nt * 16 + c) * 4);
            u32x4 t;
            t.x = g0 ? pkf16(xq.x, xq.y) : 0u;
            t.y = g0 ? pkf16(xq.z, xq.w) : 0u;
            t.z = g0 ? 0x00003C00u : 0u;    // f16 {1.0, 0}
            t.w = 0u;
            xB[nt] = __builtin_bit_cast(f16x8, t);
        }

        // ---- L1+L2 per kt: h1 chunk -> bcat B-frags -> L2 MFMAs ----
        f32x4 acc2[4][4];
#pragma unroll
        for (int mt = 0; mt < 4; ++mt) {
            f32x4 bv = *(const f32x4*)(wf + FB2 + mt * 16 + g * 4);
#pragma unroll
            for (int nt = 0; nt < 4; ++nt) acc2[mt][nt] = bv;
        }
#pragma unroll
        for (int kt = 0; kt < 4; ++kt) {
            f16x8 a0 = ldA(wh + OW1E / 2 + ((2 * kt + 0) * 16 + c) * 40 + g * 8);
            f16x8 a1 = ldA(wh + OW1E / 2 + ((2 * kt + 1) * 16 + c) * 40 + g * 8);
            f16x8 bf[4];
#pragma unroll
            for (int nt = 0; nt < 4; ++nt) {
                f32x4 z = {0.f, 0.f, 0.f, 0.f};
                f32x4 t0 = MF(a0, xB[nt], z);
                f32x4 t1 = MF(a1, xB[nt], z);
                bf[nt] = bcat(pkf16(fmaxf(t0[0], 0.f), fmaxf(t0[1], 0.f)),
                              pkf16(fmaxf(t0[2], 0.f), fmaxf(t0[3], 0.f)),
                              pkf16(fmaxf(t1[0], 0.f), fmaxf(t1[1], 0.f)),
                              pkf16(fmaxf(t1[2], 0.f), fmaxf(t1[3], 0.f)));
            }
#pragma unroll
            for (int mt = 0; mt < 4; ++mt) {
                f16x8 a = ldA(wh + OW2T / 2 + (mt * 16 + c) * 136 + kt * 32 + g * 8);
#pragma unroll
                for (int nt = 0; nt < 4; ++nt) acc2[mt][nt] = MF(a, bf[nt], acc2[mt][nt]);
            }
        }

        // ---- pack h2 (relu); acc2 dies here ----
        unsigned pk2a[4][4][2];
#pragma unroll
        for (int mt = 0; mt < 4; ++mt)
#pragma unroll
            for (int nt = 0; nt < 4; ++nt) {
                pk2a[mt][nt][0] = pkf16(fmaxf(acc2[mt][nt][0], 0.f), fmaxf(acc2[mt][nt][1], 0.f));
                pk2a[mt][nt][1] = pkf16(fmaxf(acc2[mt][nt][2], 0.f), fmaxf(acc2[mt][nt][3], 0.f));
            }

        // ---- tail FIRST: acc4 (tt) + GCN mix + out store ----
        {
            f32x4 acc4[2][4];
#pragma unroll
            for (int mt = 0; mt < 2; ++mt) {
                f32x4 bv = *(const f32x4*)(wf + FB3G + mt * 16 + g * 4);
#pragma unroll
                for (int nt = 0; nt < 4; ++nt) acc4[mt][nt] = bv;
            }
#pragma unroll
            for (int kt = 0; kt < 2; ++kt) {
#pragma unroll
                for (int mt = 0; mt < 2; ++mt) {
                    f16x8 a = ldA(wh + OW3GT / 2 + (mt * 16 + c) * 72 + kt * 32 + g * 8);
#pragma unroll
                    for (int nt = 0; nt < 4; ++nt) {
                        f16x8 bf = bcat(pk2a[2 * kt][nt][0], pk2a[2 * kt][nt][1],
                                        pk2a[2 * kt + 1][nt][0], pk2a[2 * kt + 1][nt][1]);
                        acc4[mt][nt] = MF(a, bf, acc4[mt][nt]);
                    }
                }
            }
            const f32x4 arow = *(const f32x4*)(wf + FAHAT + (c & 3) * 4);
            f32x4 bg1v[2];
            bg1v[0] = *(const f32x4*)(wf + FBG1 + g * 4);
            bg1v[1] = *(const f32x4*)(wf + FBG1 + 16 + g * 4);
            const f32x4 bg2v = *(const f32x4*)(wf + FBG2);
            const f16x8 aWg2 = ldA(wh + OWG2A / 2 + c * 40 + g * 8);
#pragma unroll
            for (int nt = 0; nt < 4; ++nt) {
                float gv[2][4];
#pragma unroll
                for (int m = 0; m < 2; ++m)
#pragma unroll
                    for (int r = 0; r < 4; ++r) {
                        float v = acc4[m][nt][r];
                        float s = bg1v[m][r];
                        s = fmaf(arow.x, qb<0>(v), s);
                        s = fmaf(arow.y, qb<1>(v), s);
                        s = fmaf(arow.z, qb<2>(v), s);
                        s = fmaf(arow.w, qb<3>(v), s);
                        gv[m][r] = fmaxf(s, 0.f);
                    }
                f16x8 bfg = bcat(pkf16(gv[0][0], gv[0][1]), pkf16(gv[0][2], gv[0][3]),
                                 pkf16(gv[1][0], gv[1][1]), pkf16(gv[1][2], gv[1][3]));
                f32x4 z = {0.f, 0.f, 0.f, 0.f};
                f32x4 u4 = MF(aWg2, bfg, z);
                float ov[4];
#pragma unroll
                for (int o = 0; o < 4; ++o) {
                    float s = bg2v[o];
                    s = fmaf(arow.x, qb<0>(u4[o]), s);
                    s = fmaf(arow.y, qb<1>(u4[o]), s);
                    s = fmaf(arow.z, qb<2>(u4[o]), s);
                    s = fmaf(arow.w, qb<3>(u4[o]), s);
                    ov[o] = s;
                }
                if (g0) {
                    f32x4 t; t.x = ov[0]; t.y = ov[1]; t.z = ov[2]; t.w = ov[3];
                    *(f32x4*)(out_out + (nbase + nt * 16 + c) * 4) = t;
                }
            }
        }

        // ---- emb in two mt-halves: acc3h[2][4] only (32 regs) ----
#pragma unroll 1
        for (int mh = 0; mh < 2; ++mh) {
            f32x4 acc3h[2][4];
#pragma unroll
            for (int mt2 = 0; mt2 < 2; ++mt2) {
                f32x4 bv = *(const f32x4*)(wf + FB3 + (mh * 2 + mt2) * 16 + g * 4);
#pragma unroll
                for (int nt = 0; nt < 4; ++nt) acc3h[mt2][nt] = bv;
            }
#pragma unroll
            for (int kt = 0; kt < 2; ++kt) {
#pragma unroll
                for (int mt2 = 0; mt2 < 2; ++mt2) {
                    const int mt = mh * 2 + mt2;
                    f16x8 a = ldA(wh + OW3T / 2 + (mt * 16 + c) * 72 + kt * 32 + g * 8);
#pragma unroll
                    for (int nt = 0; nt < 4; ++nt) {
                        f16x8 bf = bcat(pk2a[2 * kt][nt][0], pk2a[2 * kt][nt][1],
                                        pk2a[2 * kt + 1][nt][0], pk2a[2 * kt + 1][nt][1]);
                        acc3h[mt2][nt] = MF(a, bf, acc3h[mt2][nt]);
                    }
                }
            }
            // transpose half-rows via tb; store = 16 nodes x 128B full lines.
#pragma unroll
            for (int nt = 0; nt < 4; ++nt) {
#pragma unroll
                for (int mt2 = 0; mt2 < 2; ++mt2) {
                    int sl = (mt2 * 4 + g) ^ (c & 7);
                    *(f32x4*)(tb + c * 36 + sl * 4) = acc3h[mt2][nt];
                }
                float* gp = emb_out + (nbase + nt * 16) * 64 + mh * 32;
#pragma unroll
                for (int s = 0; s < 2; ++s) {
                    int F = s * 64 + lane;
                    int node = F >> 3, col4 = F & 7;
                    int sl = col4 ^ (node & 7);
                    f32x4 q = *(const f32x4*)(tb + node * 36 + sl * 4);
                    *(f32x4*)(gp + node * 64 + col4 * 4) = q;
                }
            }
        }
    }
}

// ---------------------------------------------------------------------------
extern "C" void kernel_launch(void* const* d_in, const int* in_sizes, int n_in,
                              void* d_out, int out_size, void* d_ws, size_t ws_size,
                              hipStream_t stream) {
    const float* x   = (const float*)d_in[0];
    const float* W1  = (const float*)d_in[1];
    const float* b1  = (const float*)d_in[2];
    const float* W2  = (const float*)d_in[3];
    const float* b2  = (const float*)d_in[4];
    const float* W3  = (const float*)d_in[5];
    const float* b3  = (const float*)d_in[6];
    const float* Wg1 = (const float*)d_in[7];
    const float* bg1 = (const float*)d_in[8];
    const float* Wg2 = (const float*)d_in[9];
    const float* bg2 = (const float*)d_in[10];

    unsigned int* mask_arr = (unsigned int*)d_ws;          // 4096 words, all rewritten
    char* img = (char*)d_ws + 16640;                       // past mask array, 256-aligned

    float* emb_out = (float*)d_out;
    float* out_out = emb_out + EMB_ELEMS;

    adj_kernel<<<ADJ_BLOCKS, 256, 0, stream>>>(x, mask_arr);
    prep_kernel<<<4, 256, 0, stream>>>(W1, b1, W2, b2, W3, b3, Wg1, bg1, Wg2, bg2,
                                       mask_arr, img);
    mlp_gcn_mfma<<<NNODE / 2048, 512, 0, stream>>>(x, img, emb_out, out_out);
}